// Round 6
// baseline (269.314 us; speedup 1.0000x reference)
//
#include <hip/hip_runtime.h>
#include <hip/hip_bf16.h>

typedef unsigned short u16;
typedef unsigned int u32;
typedef short bf16x8 __attribute__((ext_vector_type(8)));
typedef float f32x4 __attribute__((ext_vector_type(4)));

#define AS1 __attribute__((address_space(1)))
#define AS3 __attribute__((address_space(3)))

#define NTOK 4096
#define HDIM 512
#define FDIM 2048
#define NEXP 8
#define NASSIGN (NTOK * 2)
#define NPAD2 (NASSIGN + NEXP * 256)  // 10240
#define RBMAX 128

__device__ __forceinline__ void g2l16(const void* g, void* l) {
  __builtin_amdgcn_global_load_lds((const AS1 u32*)g, (AS3 u32*)l, 16, 0, 0);
}
__device__ __forceinline__ u16 f2bf(float f) {  // RNE fp32->bf16
  u32 u = __float_as_uint(f);
  u = (u + 0x7FFFu + ((u >> 16) & 1u)) >> 16;
  return (u16)u;
}
__device__ __forceinline__ float bf2f(u16 h) { return __uint_as_float(((u32)h) << 16); }
__device__ __forceinline__ u32 pkbf(float a, float b) {  // packed RNE pair
  __hip_bfloat162 h = __float22bfloat162_rn(float2{a, b});
  u32 r;
  __builtin_memcpy(&r, &h, 4);
  return r;
}
__device__ __forceinline__ int4 pk8(const float4 a, const float4 b) {
  int4 r;
  r.x = (int)pkbf(a.x, a.y); r.y = (int)pkbf(a.z, a.w);
  r.z = (int)pkbf(b.x, b.y); r.w = (int)pkbf(b.z, b.w);
  return r;
}

#define WAITV(N) asm volatile("s_waitcnt vmcnt(" #N ")" ::: "memory")
#define LGKM0() asm volatile("s_waitcnt lgkmcnt(0)" ::: "memory")
#define BAR() __builtin_amdgcn_s_barrier()
#define SCB() __builtin_amdgcn_sched_barrier(0)
#define PRIO1() __builtin_amdgcn_s_setprio(1)
#define PRIO0() __builtin_amdgcn_s_setprio(0)

// ---------------- Wr_eff = W_router @ W_in (fp64, exact routing) ----------------
__global__ __launch_bounds__(256) void wreff_kernel(
    const float* __restrict__ Wr, const float* __restrict__ Wi, double* __restrict__ wre) {
  const int t = blockIdx.x * 256 + threadIdx.x;  // e*512+k
  const int e = t >> 9, k = t & 511;
  const float* wr = Wr + e * HDIM;
  double a0 = 0.0, a1 = 0.0, a2 = 0.0, a3 = 0.0;
  for (int j = 0; j < HDIM; j += 4) {
    a0 += (double)wr[j + 0] * (double)Wi[(j + 0) * HDIM + k];
    a1 += (double)wr[j + 1] * (double)Wi[(j + 1) * HDIM + k];
    a2 += (double)wr[j + 2] * (double)Wi[(j + 2) * HDIM + k];
    a3 += (double)wr[j + 3] * (double)Wi[(j + 3) * HDIM + k];
  }
  wre[t] = (a0 + a1) + (a2 + a3);
}

// ---------------- router: logits = x @ Wr_eff^T (fp64), softmax, top-2 ----------------
__global__ __launch_bounds__(128) void router_kernel(
    const float* __restrict__ x, const double* __restrict__ wre,
    int* __restrict__ idx, float* __restrict__ wts) {
  __shared__ double lw[NEXP * HDIM];  // 32 KB
  for (int i = threadIdx.x; i < NEXP * HDIM; i += 128) lw[i] = wre[i];
  __syncthreads();
  const int n = blockIdx.x * 128 + threadIdx.x;
  const float* xr = x + (size_t)n * HDIM;
  double acc[NEXP] = {};
  for (int k4 = 0; k4 < HDIM / 4; ++k4) {
    const float4 xv = ((const float4*)xr)[k4];
    const float xc[4] = {xv.x, xv.y, xv.z, xv.w};
#pragma unroll
    for (int c = 0; c < 4; ++c) {
      const double xd = (double)xc[c];
#pragma unroll
      for (int e = 0; e < NEXP; ++e) acc[e] += xd * lw[e * HDIM + k4 * 4 + c];
    }
  }
  double mx = acc[0];
#pragma unroll
  for (int e = 1; e < NEXP; ++e) mx = acc[e] > mx ? acc[e] : mx;
  double p[NEXP], se = 0.0;
#pragma unroll
  for (int e = 0; e < NEXP; ++e) { p[e] = exp(acc[e] - mx); se += p[e]; }
  const double inv = 1.0 / se;
#pragma unroll
  for (int e = 0; e < NEXP; ++e) p[e] *= inv;
  int i0 = 0; double b0 = p[0];
#pragma unroll
  for (int e = 1; e < NEXP; ++e) if (p[e] > b0) { b0 = p[e]; i0 = e; }
  int i1 = -1; double b1 = -1.0;
#pragma unroll
  for (int e = 0; e < NEXP; ++e) if (e != i0 && p[e] > b1) { b1 = p[e]; i1 = e; }
  const double e0 = exp(b0), e1 = exp(b1);  // softmax OF the top-2 probabilities
  idx[2 * n] = i0; idx[2 * n + 1] = i1;
  wts[2 * n] = (float)(e0 / (e0 + e1));
  wts[2 * n + 1] = (float)(e1 / (e0 + e1));
}

// ---------------- gather lists + dual rowblock schedules (256-pad layout) ----------------
__global__ void assign_kernel(const int* __restrict__ idx, int* __restrict__ tok,
                              int* __restrict__ pos, int* __restrict__ rbe2,
                              int* __restrict__ rbp2, int* __restrict__ rbe1,
                              int* __restrict__ rbp1, int* __restrict__ nrb) {
  __shared__ int cnt[NEXP], cur[NEXP];
  const int tid = threadIdx.x;
  if (tid < NEXP) cnt[tid] = 0;
  __syncthreads();
  for (int a = tid; a < NASSIGN; a += 256) atomicAdd(&cnt[idx[a]], 1);
  __syncthreads();
  if (tid == 0) {
    int o = 0, n2 = 0, n1 = 0;
    for (int e = 0; e < NEXP; ++e) {
      cur[e] = o;
      const int nb2 = (cnt[e] + 255) >> 8;
      const int nb1 = (cnt[e] + 127) >> 7;
      for (int i = 0; i < nb2; ++i) { rbe2[n2] = e; rbp2[n2] = o + i * 256; ++n2; }
      for (int i = 0; i < nb1; ++i) { rbe1[n1] = e; rbp1[n1] = o + i * 128; ++n1; }
      o += nb2 * 256;
    }
    nrb[0] = n2; nrb[1] = n1;
  }
  __syncthreads();
  for (int p = tid; p < NPAD2; p += 256) tok[p] = 0;  // pad rows -> token 0 (never read back)
  __syncthreads();
  for (int a = tid; a < NASSIGN; a += 256) {
    const int e = idx[a];
    const int q = atomicAdd(&cur[e], 1);
    tok[q] = a >> 1;
    pos[a] = q;
  }
}

// ---- ingemm: h = x @ Wi^T, both operands fp32 reg-staged -> bf16 LDS, 128x128, BK=64 ----
__global__ __launch_bounds__(512, 2) void ingemm_kernel(
    const float* __restrict__ x, const float* __restrict__ Wi, u16* __restrict__ hb) {
  __shared__ __align__(16) u16 sm[32768];  // 64 KB: 2 x (A[128][64] | B[128][64])
  const int m0 = blockIdx.y * 128, n0 = blockIdx.x * 128;
  const int tid = threadIdx.x, w = tid >> 6, l = tid & 63;
  const int wm = (w >> 2) * 64, wn = (w & 3) * 32;
  const int lm = l & 15, lk = (l >> 4) * 8, xr = (l & 7) * 8;
  const int lr = l >> 3, c8 = l & 7;
  const int ko0 = lk ^ xr, ko1 = (32 + lk) ^ xr;
  const int wcol = (c8 ^ lr) * 8;
  const float* Ap0 = x + (size_t)(m0 + w * 8 + lr) * HDIM + c8 * 8;
  const float* Ap1 = Ap0 + (size_t)64 * HDIM;
  const float* Bp0 = Wi + (size_t)(n0 + w * 8 + lr) * HDIM + c8 * 8;
  const float* Bp1 = Bp0 + (size_t)64 * HDIM;
  f32x4 acc[4][2] = {};
  float4 v0, v1, v2, v3, v4, v5, v6, v7;
  auto WLOAD = [&](int kt) {
    v0 = *(const float4*)(Ap0 + kt); v1 = *(const float4*)(Ap0 + kt + 4);
    v2 = *(const float4*)(Ap1 + kt); v3 = *(const float4*)(Ap1 + kt + 4);
    v4 = *(const float4*)(Bp0 + kt); v5 = *(const float4*)(Bp0 + kt + 4);
    v6 = *(const float4*)(Bp1 + kt); v7 = *(const float4*)(Bp1 + kt + 4);
  };
  auto WWRITE = [&](u16* st) {
    *(int4*)(st + (w * 8 + lr) * 64 + wcol) = pk8(v0, v1);
    *(int4*)(st + (64 + w * 8 + lr) * 64 + wcol) = pk8(v2, v3);
    *(int4*)(st + 8192 + (w * 8 + lr) * 64 + wcol) = pk8(v4, v5);
    *(int4*)(st + 8192 + (64 + w * 8 + lr) * 64 + wcol) = pk8(v6, v7);
  };
  WLOAD(0);
  WAITV(0); WWRITE(sm);
  LGKM0(); BAR(); SCB();
  for (int t = 0; t < 8; ++t) {
    u16* bu = sm + (t & 1) * 16384;
    u16* bn = sm + ((t + 1) & 1) * 16384;
    if (t < 7) WLOAD((t + 1) * 64);
    const u16 *a_ = bu, *b_ = bu + 8192;
#pragma unroll
    for (int kk = 0; kk < 2; ++kk) {
      const int ko = kk ? ko1 : ko0;
      bf16x8 af[4], bf[2];
#pragma unroll
      for (int i = 0; i < 4; ++i) af[i] = *(const bf16x8*)(a_ + (wm + i * 16 + lm) * 64 + ko);
#pragma unroll
      for (int j = 0; j < 2; ++j) bf[j] = *(const bf16x8*)(b_ + (wn + j * 16 + lm) * 64 + ko);
      PRIO1();
#pragma unroll
      for (int i = 0; i < 4; ++i)
#pragma unroll
        for (int j = 0; j < 2; ++j)
          acc[i][j] = __builtin_amdgcn_mfma_f32_16x16x32_bf16(af[i], bf[j], acc[i][j], 0, 0, 0);
      PRIO0();
    }
    if (t < 7) { WAITV(0); WWRITE(bn); }
    LGKM0(); BAR(); SCB();
  }
  const int cr = (l >> 4) * 4, cc = lm;
#pragma unroll
  for (int i = 0; i < 4; ++i)
#pragma unroll
    for (int j = 0; j < 2; ++j)
#pragma unroll
      for (int r = 0; r < 4; ++r)
        hb[(size_t)(m0 + wm + i * 16 + cr + r) * HDIM + n0 + wn + j * 16 + cc] =
            f2bf(acc[i][j][r]);
}

// ---- outgemm: out = cb @ Wo^T, A bf16 g2l, B fp32 reg-staged, fp32 out ----
__global__ __launch_bounds__(512, 2) void outgemm_kernel(
    const u16* __restrict__ cb, const float* __restrict__ Wo, float* __restrict__ out) {
  __shared__ __align__(16) u16 sm[32768];  // 64 KB
  const int m0 = blockIdx.y * 128, n0 = blockIdx.x * 128;
  const int tid = threadIdx.x, w = tid >> 6, l = tid & 63;
  const int wm = (w >> 2) * 64, wn = (w & 3) * 32;
  const int lm = l & 15, lk = (l >> 4) * 8, xr = (l & 7) * 8;
  const int lr = l >> 3, c8 = l & 7;
  const int ko0 = lk ^ xr, ko1 = (32 + lk) ^ xr;
  const int wcol = (c8 ^ lr) * 8;
  const u16* Ap0 = cb + (size_t)(m0 + w * 8 + lr) * HDIM + wcol;  // pre-swizzled src
  const u16* Ap1 = Ap0 + (size_t)64 * HDIM;
  const float* Bp0 = Wo + (size_t)(n0 + w * 8 + lr) * HDIM + c8 * 8;
  const float* Bp1 = Bp0 + (size_t)64 * HDIM;
  f32x4 acc[4][2] = {};
  float4 v4, v5, v6, v7;
  auto WLOADB = [&](int kt) {
    v4 = *(const float4*)(Bp0 + kt); v5 = *(const float4*)(Bp0 + kt + 4);
    v6 = *(const float4*)(Bp1 + kt); v7 = *(const float4*)(Bp1 + kt + 4);
  };
  auto WWRITEB = [&](u16* st) {
    *(int4*)(st + 8192 + (w * 8 + lr) * 64 + wcol) = pk8(v4, v5);
    *(int4*)(st + 8192 + (64 + w * 8 + lr) * 64 + wcol) = pk8(v6, v7);
  };
  auto STGA = [&](u16* st, int kt) {
    g2l16(Ap0 + kt, st + w * 512);
    g2l16(Ap1 + kt, st + 4096 + w * 512);
  };
  WLOADB(0); SCB(); STGA(sm, 0);
  WAITV(2); WWRITEB(sm);
  WAITV(0); LGKM0(); BAR(); SCB();
  for (int t = 0; t < 8; ++t) {
    u16* bu = sm + (t & 1) * 16384;
    u16* bn = sm + ((t + 1) & 1) * 16384;
    if (t < 7) { WLOADB((t + 1) * 64); SCB(); STGA(bn, (t + 1) * 64); }
    const u16 *a_ = bu, *b_ = bu + 8192;
#pragma unroll
    for (int kk = 0; kk < 2; ++kk) {
      const int ko = kk ? ko1 : ko0;
      bf16x8 af[4], bf[2];
#pragma unroll
      for (int i = 0; i < 4; ++i) af[i] = *(const bf16x8*)(a_ + (wm + i * 16 + lm) * 64 + ko);
#pragma unroll
      for (int j = 0; j < 2; ++j) bf[j] = *(const bf16x8*)(b_ + (wn + j * 16 + lm) * 64 + ko);
      PRIO1();
#pragma unroll
      for (int i = 0; i < 4; ++i)
#pragma unroll
        for (int j = 0; j < 2; ++j)
          acc[i][j] = __builtin_amdgcn_mfma_f32_16x16x32_bf16(af[i], bf[j], acc[i][j], 0, 0, 0);
      PRIO0();
    }
    if (t < 7) { WAITV(2); WWRITEB(bn); WAITV(0); }
    LGKM0(); BAR(); SCB();
  }
  const int cr = (l >> 4) * 4, cc = lm;
#pragma unroll
  for (int i = 0; i < 4; ++i)
#pragma unroll
    for (int j = 0; j < 2; ++j)
#pragma unroll
      for (int r = 0; r < 4; ++r)
        out[(size_t)(m0 + wm + i * 16 + cr + r) * HDIM + n0 + wn + j * 16 + cc] = acc[i][j][r];
}

// ---- gateup: 256 rows x (128G+128U), 8 waves 64x(64+64), BK=64, 2-stage 128 KB,
// ---- A bf16 via g2l, weights fp32 reg-staged -> cvt -> swizzled ds_write ----
__global__ __launch_bounds__(512, 2) void gateup_kernel(
    const u16* __restrict__ hb, const float* __restrict__ Wg, const float* __restrict__ Wu,
    u16* __restrict__ act, const int* __restrict__ tok, const int* __restrict__ rbe2,
    const int* __restrict__ rbp2, const int* __restrict__ nrb) {
  const int rb = blockIdx.y;
  if (rb >= nrb[0]) return;
  __shared__ __align__(16) u16 sm[65536];  // 128 KB: 2 x (A 16384 | G 8192 | U 8192 elems)
  const int e = rbe2[rb], p0 = rbp2[rb], n0 = blockIdx.x * 128;
  const int tid = threadIdx.x, w = tid >> 6, l = tid & 63;
  const int wr = w >> 1, wc = w & 1;
  const int lm = l & 15, lk = (l >> 4) * 8, xr = (l & 7) * 8;
  const int lr = l >> 3, c8 = l & 7;
  const int ko0 = lk ^ xr, ko1 = (32 + lk) ^ xr;
  const int wcol = (c8 ^ lr) * 8;
  const u16* Asrc[4];
#pragma unroll
  for (int c = 0; c < 4; ++c)
    Asrc[c] = hb + (size_t)tok[p0 + c * 64 + w * 8 + lr] * HDIM + wcol;  // pre-swizzled src
  const float* Gp0 = Wg + (size_t)e * FDIM * HDIM + (size_t)(n0 + w * 8 + lr) * HDIM + c8 * 8;
  const float* Gp1 = Gp0 + (size_t)64 * HDIM;
  const float* Up0 = Wu + (size_t)e * FDIM * HDIM + (size_t)(n0 + w * 8 + lr) * HDIM + c8 * 8;
  const float* Up1 = Up0 + (size_t)64 * HDIM;
  f32x4 ag[4][4] = {}, au[4][4] = {};
  float4 g0, g1, g2, g3, u0, u1, u2, u3;
  auto WLOAD = [&](int kt) {  // 8 dwordx4 fp32
    g0 = *(const float4*)(Gp0 + kt); g1 = *(const float4*)(Gp0 + kt + 4);
    g2 = *(const float4*)(Gp1 + kt); g3 = *(const float4*)(Gp1 + kt + 4);
    u0 = *(const float4*)(Up0 + kt); u1 = *(const float4*)(Up0 + kt + 4);
    u2 = *(const float4*)(Up1 + kt); u3 = *(const float4*)(Up1 + kt + 4);
  };
  auto WWRITE = [&](u16* st) {  // cvt + 4 swizzled ds_write_b128
    u16* dG = st + 16384;
    u16* dU = st + 24576;
    *(int4*)(dG + (w * 8 + lr) * 64 + wcol) = pk8(g0, g1);
    *(int4*)(dG + (64 + w * 8 + lr) * 64 + wcol) = pk8(g2, g3);
    *(int4*)(dU + (w * 8 + lr) * 64 + wcol) = pk8(u0, u1);
    *(int4*)(dU + (64 + w * 8 + lr) * 64 + wcol) = pk8(u2, u3);
  };
  auto STGA = [&](u16* st, int kt) {  // 4 g2l16 bf16
#pragma unroll
    for (int c = 0; c < 4; ++c) g2l16(Asrc[c] + kt, st + c * 4096 + w * 512);
  };
  WLOAD(0); SCB(); STGA(sm, 0);
  WAITV(4); WWRITE(sm);
  WAITV(0); LGKM0(); BAR(); SCB();
#pragma unroll 2
  for (int t = 0; t < 8; ++t) {
    u16* bu = sm + (t & 1) * 32768;
    u16* bn = sm + ((t + 1) & 1) * 32768;
    const u16 *A_ = bu, *G_ = bu + 16384, *U_ = bu + 24576;
    bf16x8 af[4], gf[4], uf[4];
    // P1: af+gf @kk0, issue next weight loads, MFMA ag
#pragma unroll
    for (int i = 0; i < 4; ++i) af[i] = *(const bf16x8*)(A_ + (wr * 64 + i * 16 + lm) * 64 + ko0);
#pragma unroll
    for (int j = 0; j < 4; ++j) gf[j] = *(const bf16x8*)(G_ + (wc * 64 + j * 16 + lm) * 64 + ko0);
    if (t < 7) WLOAD((t + 1) * 64);
    PRIO1();
#pragma unroll
    for (int i = 0; i < 4; ++i)
#pragma unroll
      for (int j = 0; j < 4; ++j)
        ag[i][j] = __builtin_amdgcn_mfma_f32_16x16x32_bf16(af[i], gf[j], ag[i][j], 0, 0, 0);
    PRIO0();
    BAR(); SCB();
    // P2: uf @kk0, issue next A g2l, MFMA au
#pragma unroll
    for (int j = 0; j < 4; ++j) uf[j] = *(const bf16x8*)(U_ + (wc * 64 + j * 16 + lm) * 64 + ko0);
    if (t < 7) STGA(bn, (t + 1) * 64);
    PRIO1();
#pragma unroll
    for (int i = 0; i < 4; ++i)
#pragma unroll
      for (int j = 0; j < 4; ++j)
        au[i][j] = __builtin_amdgcn_mfma_f32_16x16x32_bf16(af[i], uf[j], au[i][j], 0, 0, 0);
    PRIO0();
    BAR(); SCB();
    // P3: af+gf @kk1, weights landed (4 g2l still in flight) -> cvt+ds_write, MFMA ag
#pragma unroll
    for (int i = 0; i < 4; ++i) af[i] = *(const bf16x8*)(A_ + (wr * 64 + i * 16 + lm) * 64 + ko1);
#pragma unroll
    for (int j = 0; j < 4; ++j) gf[j] = *(const bf16x8*)(G_ + (wc * 64 + j * 16 + lm) * 64 + ko1);
    if (t < 7) { WAITV(4); WWRITE(bn); }
    PRIO1();
#pragma unroll
    for (int i = 0; i < 4; ++i)
#pragma unroll
      for (int j = 0; j < 4; ++j)
        ag[i][j] = __builtin_amdgcn_mfma_f32_16x16x32_bf16(af[i], gf[j], ag[i][j], 0, 0, 0);
    PRIO0();
    BAR(); SCB();
    // P4: uf @kk1, MFMA au, drain A g2l + publish ds_writes
#pragma unroll
    for (int j = 0; j < 4; ++j) uf[j] = *(const bf16x8*)(U_ + (wc * 64 + j * 16 + lm) * 64 + ko1);
    PRIO1();
#pragma unroll
    for (int i = 0; i < 4; ++i)
#pragma unroll
      for (int j = 0; j < 4; ++j)
        au[i][j] = __builtin_amdgcn_mfma_f32_16x16x32_bf16(af[i], uf[j], au[i][j], 0, 0, 0);
    PRIO0();
    if (t < 7) WAITV(0);
    LGKM0(); BAR(); SCB();
  }
  const int cr = (l >> 4) * 4, cc = lm;
#pragma unroll
  for (int i = 0; i < 4; ++i)
#pragma unroll
    for (int j = 0; j < 4; ++j)
#pragma unroll
      for (int r = 0; r < 4; ++r) {
        const float g = ag[i][j][r], u = au[i][j][r];
        const float s = g / (1.0f + __expf(-g));
        act[(size_t)(p0 + wr * 64 + i * 16 + cr + r) * FDIM + n0 + wc * 64 + j * 16 + cc] =
            f2bf(s * u);
      }
}

// ---- down: 128x128, 4 waves 64x64, BK=64 (32 tiles), 2-stage 64 KB -> 2 blk/CU ----
__global__ __launch_bounds__(256, 2) void down_kernel(
    const u16* __restrict__ act, const float* __restrict__ Wd, u16* __restrict__ dwn,
    const int* __restrict__ rbe1, const int* __restrict__ rbp1, const int* __restrict__ nrb) {
  const int rb = blockIdx.y;
  if (rb >= nrb[1]) return;
  __shared__ __align__(16) u16 sm[32768];  // 64 KB: 2 x (A 8192 | B 8192 elems)
  const int e = rbe1[rb], p0 = rbp1[rb], n0 = blockIdx.x * 128;
  const int tid = threadIdx.x, w = tid >> 6, l = tid & 63;
  const int wr = w >> 1, wc = w & 1;
  const int lm = l & 15, lk = (l >> 4) * 8, xr = (l & 7) * 8;
  const int lr = l >> 3, c8 = l & 7;
  const int ko0 = lk ^ xr, ko1 = (32 + lk) ^ xr;
  const int wcol = (c8 ^ lr) * 8;
  const u16* Asrc[4];
#pragma unroll
  for (int c = 0; c < 4; ++c)
    Asrc[c] = act + (size_t)(p0 + c * 32 + w * 8 + lr) * FDIM + wcol;  // pre-swizzled src
  const float* Bp[4];
#pragma unroll
  for (int c = 0; c < 4; ++c)
    Bp[c] = Wd + (size_t)e * HDIM * FDIM + (size_t)(n0 + c * 32 + w * 8 + lr) * FDIM + c8 * 8;
  f32x4 acc[4][4] = {};
  float4 b0, b1, b2, b3, b4, b5, b6, b7;
  auto WLOAD = [&](int kt) {  // 8 dwordx4 fp32
    b0 = *(const float4*)(Bp[0] + kt); b1 = *(const float4*)(Bp[0] + kt + 4);
    b2 = *(const float4*)(Bp[1] + kt); b3 = *(const float4*)(Bp[1] + kt + 4);
    b4 = *(const float4*)(Bp[2] + kt); b5 = *(const float4*)(Bp[2] + kt + 4);
    b6 = *(const float4*)(Bp[3] + kt); b7 = *(const float4*)(Bp[3] + kt + 4);
  };
  auto WWRITE = [&](u16* st) {
    u16* dB = st + 8192;
    *(int4*)(dB + (w * 8 + lr) * 64 + wcol) = pk8(b0, b1);
    *(int4*)(dB + (32 + w * 8 + lr) * 64 + wcol) = pk8(b2, b3);
    *(int4*)(dB + (64 + w * 8 + lr) * 64 + wcol) = pk8(b4, b5);
    *(int4*)(dB + (96 + w * 8 + lr) * 64 + wcol) = pk8(b6, b7);
  };
  auto STGA = [&](u16* st, int kt) {
#pragma unroll
    for (int c = 0; c < 4; ++c) g2l16(Asrc[c] + kt, st + c * 2048 + w * 512);
  };
  WLOAD(0); SCB(); STGA(sm, 0);
  WAITV(4); WWRITE(sm);
  WAITV(0); LGKM0(); BAR(); SCB();
#pragma unroll 2
  for (int t = 0; t < 32; ++t) {
    u16* bu = sm + (t & 1) * 16384;
    u16* bn = sm + ((t + 1) & 1) * 16384;
    const u16 *A_ = bu, *B_ = bu + 8192;
    bf16x8 af[4], bf[4];
    // P1: kk0, issue next (weights first, then A g2l)
#pragma unroll
    for (int i = 0; i < 4; ++i) af[i] = *(const bf16x8*)(A_ + (wr * 64 + i * 16 + lm) * 64 + ko0);
#pragma unroll
    for (int j = 0; j < 4; ++j) bf[j] = *(const bf16x8*)(B_ + (wc * 64 + j * 16 + lm) * 64 + ko0);
    if (t < 31) { WLOAD((t + 1) * 64); SCB(); STGA(bn, (t + 1) * 64); }
    PRIO1();
#pragma unroll
    for (int i = 0; i < 4; ++i)
#pragma unroll
      for (int j = 0; j < 4; ++j)
        acc[i][j] = __builtin_amdgcn_mfma_f32_16x16x32_bf16(af[i], bf[j], acc[i][j], 0, 0, 0);
    PRIO0();
    BAR(); SCB();
    // P2: kk1, weights ready -> cvt+ds_write, drain
#pragma unroll
    for (int i = 0; i < 4; ++i) af[i] = *(const bf16x8*)(A_ + (wr * 64 + i * 16 + lm) * 64 + ko1);
#pragma unroll
    for (int j = 0; j < 4; ++j) bf[j] = *(const bf16x8*)(B_ + (wc * 64 + j * 16 + lm) * 64 + ko1);
    if (t < 31) { WAITV(4); WWRITE(bn); }
    PRIO1();
#pragma unroll
    for (int i = 0; i < 4; ++i)
#pragma unroll
      for (int j = 0; j < 4; ++j)
        acc[i][j] = __builtin_amdgcn_mfma_f32_16x16x32_bf16(af[i], bf[j], acc[i][j], 0, 0, 0);
    PRIO0();
    if (t < 31) WAITV(0);
    LGKM0(); BAR(); SCB();
  }
  const int cr = (l >> 4) * 4, cc = lm;
#pragma unroll
  for (int i = 0; i < 4; ++i)
#pragma unroll
    for (int j = 0; j < 4; ++j)
#pragma unroll
      for (int r = 0; r < 4; ++r)
        dwn[(size_t)(p0 + wr * 64 + i * 16 + cr + r) * HDIM + n0 + wc * 64 + j * 16 + cc] =
            f2bf(acc[i][j][r]);
}

// ---------------- combine: c[n] = w0*down[pos0] + w1*down[pos1] (bf16 in/out) ----------------
__global__ void combine_kernel(const u16* __restrict__ dwn, const int* __restrict__ pos,
                               const float* __restrict__ wts, u16* __restrict__ cb) {
  const int n = blockIdx.x, t = threadIdx.x;  // 128 threads x 4 elems
  const int p0 = pos[2 * n], p1 = pos[2 * n + 1];
  const float w0 = wts[2 * n], w1 = wts[2 * n + 1];
  const ushort4 a = ((const ushort4*)(dwn + (size_t)p0 * HDIM))[t];
  const ushort4 b = ((const ushort4*)(dwn + (size_t)p1 * HDIM))[t];
  ushort4 o;
  o.x = f2bf(w0 * bf2f(a.x) + w1 * bf2f(b.x));
  o.y = f2bf(w0 * bf2f(a.y) + w1 * bf2f(b.y));
  o.z = f2bf(w0 * bf2f(a.z) + w1 * bf2f(b.z));
  o.w = f2bf(w0 * bf2f(a.w) + w1 * bf2f(b.w));
  ((ushort4*)(cb + (size_t)n * HDIM))[t] = o;
}

extern "C" void kernel_launch(void* const* d_in, const int* in_sizes, int n_in,
                              void* d_out, int out_size, void* d_ws, size_t ws_size,
                              hipStream_t stream) {
  const float* x  = (const float*)d_in[0];
  const float* Wi = (const float*)d_in[1];
  const float* Wr = (const float*)d_in[2];
  const float* Wg = (const float*)d_in[3];
  const float* Wu = (const float*)d_in[4];
  const float* Wd = (const float*)d_in[5];
  const float* Wo = (const float*)d_in[6];
  float* out = (float*)d_out;

  char* ws = (char*)d_ws;
  size_t off = 0;
  auto alloc = [&](size_t bytes) -> void* {
    off = (off + 255) & ~(size_t)255;
    void* p = ws + off;
    off += bytes;
    return p;
  };
  u16* hb   = (u16*)alloc((size_t)NTOK * HDIM * 2);
  u16* cb   = (u16*)alloc((size_t)NTOK * HDIM * 2);
  u16* actb = (u16*)alloc((size_t)NPAD2 * FDIM * 2);
  u16* dwn  = (u16*)alloc((size_t)NPAD2 * HDIM * 2);
  double* wre = (double*)alloc((size_t)NEXP * HDIM * 8);
  int* idx = (int*)alloc((size_t)NASSIGN * 4);
  float* wts = (float*)alloc((size_t)NASSIGN * 4);
  int* tok = (int*)alloc((size_t)NPAD2 * 4);
  int* pos = (int*)alloc((size_t)NASSIGN * 4);
  int* rbe2 = (int*)alloc((size_t)RBMAX * 4);
  int* rbp2 = (int*)alloc((size_t)RBMAX * 4);
  int* rbe1 = (int*)alloc((size_t)RBMAX * 4);
  int* rbp1 = (int*)alloc((size_t)RBMAX * 4);
  int* nrb = (int*)alloc(256);

  wreff_kernel<<<16, 256, 0, stream>>>(Wr, Wi, wre);
  router_kernel<<<32, 128, 0, stream>>>(x, wre, idx, wts);
  assign_kernel<<<1, 256, 0, stream>>>(idx, tok, pos, rbe2, rbp2, rbe1, rbp1, nrb);
  ingemm_kernel<<<dim3(4, 32), 512, 0, stream>>>(x, Wi, hb);
  gateup_kernel<<<dim3(16, 40), 512, 0, stream>>>(hb, Wg, Wu, actb, tok, rbe2, rbp2, nrb);
  down_kernel<<<dim3(4, 72), 256, 0, stream>>>(actb, Wd, dwn, rbe1, rbp1, nrb);
  combine_kernel<<<NTOK, 128, 0, stream>>>(dwn, pos, wts, cb);
  outgemm_kernel<<<dim3(4, 32), 512, 0, stream>>>(cb, Wo, out);
}

// Round 7
// 233.295 us; speedup vs baseline: 1.1544x; 1.1544x over previous
//
#include <hip/hip_runtime.h>
#include <hip/hip_bf16.h>

typedef unsigned short u16;
typedef unsigned int u32;
typedef short bf16x8 __attribute__((ext_vector_type(8)));
typedef float f32x4 __attribute__((ext_vector_type(4)));

#define AS1 __attribute__((address_space(1)))
#define AS3 __attribute__((address_space(3)))

#define NTOK 4096
#define HDIM 512
#define FDIM 2048
#define NEXP 8
#define NASSIGN (NTOK * 2)
#define NPAD (NASSIGN + NEXP * 128)  // 9216, 128-padded rows upper bound
#define RBMAX 128

__device__ __forceinline__ void g2l16(const void* g, void* l) {
  __builtin_amdgcn_global_load_lds((const AS1 u32*)g, (AS3 u32*)l, 16, 0, 0);
}
__device__ __forceinline__ u16 f2bf(float f) {  // RNE fp32->bf16
  u32 u = __float_as_uint(f);
  u = (u + 0x7FFFu + ((u >> 16) & 1u)) >> 16;
  return (u16)u;
}
__device__ __forceinline__ float bf2f(u16 h) { return __uint_as_float(((u32)h) << 16); }
__device__ __forceinline__ u32 pkbf(float a, float b) {  // v_cvt_pk_bf16_f32 (RNE)
  __hip_bfloat162 h = __float22bfloat162_rn(float2{a, b});
  u32 r;
  __builtin_memcpy(&r, &h, 4);
  return r;
}
__device__ __forceinline__ int4 pk8(const float4 a, const float4 b) {
  int4 r;
  r.x = (int)pkbf(a.x, a.y); r.y = (int)pkbf(a.z, a.w);
  r.z = (int)pkbf(b.x, b.y); r.w = (int)pkbf(b.z, b.w);
  return r;
}

#define WAITV6() asm volatile("s_waitcnt vmcnt(6)" ::: "memory")
#define WAITV4() asm volatile("s_waitcnt vmcnt(4)" ::: "memory")
#define WAITV2() asm volatile("s_waitcnt vmcnt(2)" ::: "memory")
#define WAITV0() asm volatile("s_waitcnt vmcnt(0)" ::: "memory")
#define LGKM0() asm volatile("s_waitcnt lgkmcnt(0)" ::: "memory")
#define BAR() __builtin_amdgcn_s_barrier()
#define SCB() __builtin_amdgcn_sched_barrier(0)
#define PRIO1() __builtin_amdgcn_s_setprio(1)
#define PRIO0() __builtin_amdgcn_s_setprio(0)
#define VMBAR() do { WAITV0(); BAR(); } while (0)

// ---- cvtw: fp32->bf16 for Wg/Wu/Wd only. 32B/lane reads, 16B/lane stores, 6x unroll ----
// pairs per tensor = 2097152 float4 / 2 = 1048576 (2^20); total pairs 3145728 = 6 x 524288
__global__ __launch_bounds__(256) void cvtw_kernel(
    const float* __restrict__ Wg, const float* __restrict__ Wu, const float* __restrict__ Wd,
    u16* __restrict__ Wgb, u16* __restrict__ Wub, u16* __restrict__ Wdb) {
  const int gid = blockIdx.x * 256 + threadIdx.x;  // 524288 threads
  const float* sp[6];
  u16* dp[6];
#pragma unroll
  for (int i = 0; i < 6; ++i) {
    const int p = gid + i * 524288;
    const int seg = p >> 20;
    const size_t off = (size_t)(p & 1048575) * 8;
    const float* s = (seg == 0) ? Wg : (seg == 1) ? Wu : Wd;
    u16* d = (seg == 0) ? Wgb : (seg == 1) ? Wub : Wdb;
    sp[i] = s + off;
    dp[i] = d + off;
  }
  float4 a[12];
#pragma unroll
  for (int i = 0; i < 6; ++i) {
    a[2 * i] = ((const float4*)sp[i])[0];
    a[2 * i + 1] = ((const float4*)sp[i])[1];
  }
#pragma unroll
  for (int i = 0; i < 6; ++i) *(int4*)dp[i] = pk8(a[2 * i], a[2 * i + 1]);
}

// ---------------- Wr_eff = W_router @ W_in (fp64, exact routing) ----------------
__global__ __launch_bounds__(256) void wreff_kernel(
    const float* __restrict__ Wr, const float* __restrict__ Wi, double* __restrict__ wre) {
  const int t = blockIdx.x * 256 + threadIdx.x;  // e*512+k
  const int e = t >> 9, k = t & 511;
  const float* wr = Wr + e * HDIM;
  double a0 = 0.0, a1 = 0.0, a2 = 0.0, a3 = 0.0;
  for (int j = 0; j < HDIM; j += 4) {
    a0 += (double)wr[j + 0] * (double)Wi[(j + 0) * HDIM + k];
    a1 += (double)wr[j + 1] * (double)Wi[(j + 1) * HDIM + k];
    a2 += (double)wr[j + 2] * (double)Wi[(j + 2) * HDIM + k];
    a3 += (double)wr[j + 3] * (double)Wi[(j + 3) * HDIM + k];
  }
  wre[t] = (a0 + a1) + (a2 + a3);
}

// ---------------- router: logits = x @ Wr_eff^T (fp64), softmax, top-2 ----------------
__global__ __launch_bounds__(128) void router_kernel(
    const float* __restrict__ x, const double* __restrict__ wre,
    int* __restrict__ idx, float* __restrict__ wts) {
  __shared__ double lw[NEXP * HDIM];  // 32 KB
  for (int i = threadIdx.x; i < NEXP * HDIM; i += 128) lw[i] = wre[i];
  __syncthreads();
  const int n = blockIdx.x * 128 + threadIdx.x;
  const float* xr = x + (size_t)n * HDIM;
  double acc[NEXP] = {};
  for (int k4 = 0; k4 < HDIM / 4; ++k4) {
    const float4 xv = ((const float4*)xr)[k4];
    const float xc[4] = {xv.x, xv.y, xv.z, xv.w};
#pragma unroll
    for (int c = 0; c < 4; ++c) {
      const double xd = (double)xc[c];
#pragma unroll
      for (int e = 0; e < NEXP; ++e) acc[e] += xd * lw[e * HDIM + k4 * 4 + c];
    }
  }
  double mx = acc[0];
#pragma unroll
  for (int e = 1; e < NEXP; ++e) mx = acc[e] > mx ? acc[e] : mx;
  double p[NEXP], se = 0.0;
#pragma unroll
  for (int e = 0; e < NEXP; ++e) { p[e] = exp(acc[e] - mx); se += p[e]; }
  const double inv = 1.0 / se;
#pragma unroll
  for (int e = 0; e < NEXP; ++e) p[e] *= inv;
  int i0 = 0; double b0 = p[0];
#pragma unroll
  for (int e = 1; e < NEXP; ++e) if (p[e] > b0) { b0 = p[e]; i0 = e; }
  int i1 = -1; double b1 = -1.0;
#pragma unroll
  for (int e = 0; e < NEXP; ++e) if (e != i0 && p[e] > b1) { b1 = p[e]; i1 = e; }
  const double e0 = exp(b0), e1 = exp(b1);  // softmax OF the top-2 probabilities
  idx[2 * n] = i0; idx[2 * n + 1] = i1;
  wts[2 * n] = (float)(e0 / (e0 + e1));
  wts[2 * n + 1] = (float)(e1 / (e0 + e1));
}

// ---------------- gather lists + 128-padded rowblock schedule ----------------
__global__ void assign_kernel(const int* __restrict__ idx, int* __restrict__ tok,
                              int* __restrict__ pos, int* __restrict__ rbe,
                              int* __restrict__ rbp, int* __restrict__ nrb) {
  __shared__ int cnt[NEXP], cur[NEXP];
  const int tid = threadIdx.x;
  if (tid < NEXP) cnt[tid] = 0;
  __syncthreads();
  for (int a = tid; a < NASSIGN; a += 256) atomicAdd(&cnt[idx[a]], 1);
  __syncthreads();
  if (tid == 0) {
    int o = 0, n = 0;
    for (int e = 0; e < NEXP; ++e) {
      cur[e] = o;
      const int nb = (cnt[e] + 127) >> 7;
      for (int i = 0; i < nb; ++i) { rbe[n] = e; rbp[n] = o + i * 128; ++n; }
      o += nb * 128;
    }
    nrb[0] = n;
  }
  __syncthreads();
  for (int p = tid; p < NPAD; p += 256) tok[p] = 0;  // pad rows -> token 0 (never read back)
  __syncthreads();
  for (int a = tid; a < NASSIGN; a += 256) {
    const int e = idx[a];
    const int q = atomicAdd(&cur[e], 1);
    tok[q] = a >> 1;
    pos[a] = q;
  }
}

// ---- ingemm: h = x @ Wi^T, fp32 reg-staged -> bf16 LDS (r6-proven), 128x128, BK=64 ----
__global__ __launch_bounds__(512, 2) void ingemm_kernel(
    const float* __restrict__ x, const float* __restrict__ Wi, u16* __restrict__ hb) {
  __shared__ __align__(16) u16 sm[32768];  // 64 KB: 2 x (A[128][64] | B[128][64])
  const int m0 = blockIdx.y * 128, n0 = blockIdx.x * 128;
  const int tid = threadIdx.x, w = tid >> 6, l = tid & 63;
  const int wm = (w >> 2) * 64, wn = (w & 3) * 32;
  const int lm = l & 15, lk = (l >> 4) * 8, xr = (l & 7) * 8;
  const int lr = l >> 3, c8 = l & 7;
  const int ko0 = lk ^ xr, ko1 = (32 + lk) ^ xr;
  const int wcol = (c8 ^ lr) * 8;
  const float* Ap0 = x + (size_t)(m0 + w * 8 + lr) * HDIM + c8 * 8;
  const float* Ap1 = Ap0 + (size_t)64 * HDIM;
  const float* Bp0 = Wi + (size_t)(n0 + w * 8 + lr) * HDIM + c8 * 8;
  const float* Bp1 = Bp0 + (size_t)64 * HDIM;
  f32x4 acc[4][2] = {};
  float4 v0, v1, v2, v3, v4, v5, v6, v7;
  auto WLOAD = [&](int kt) {
    v0 = *(const float4*)(Ap0 + kt); v1 = *(const float4*)(Ap0 + kt + 4);
    v2 = *(const float4*)(Ap1 + kt); v3 = *(const float4*)(Ap1 + kt + 4);
    v4 = *(const float4*)(Bp0 + kt); v5 = *(const float4*)(Bp0 + kt + 4);
    v6 = *(const float4*)(Bp1 + kt); v7 = *(const float4*)(Bp1 + kt + 4);
  };
  auto WWRITE = [&](u16* st) {
    *(int4*)(st + (w * 8 + lr) * 64 + wcol) = pk8(v0, v1);
    *(int4*)(st + (64 + w * 8 + lr) * 64 + wcol) = pk8(v2, v3);
    *(int4*)(st + 8192 + (w * 8 + lr) * 64 + wcol) = pk8(v4, v5);
    *(int4*)(st + 8192 + (64 + w * 8 + lr) * 64 + wcol) = pk8(v6, v7);
  };
  WLOAD(0);
  WAITV0(); WWRITE(sm);
  LGKM0(); BAR(); SCB();
  for (int t = 0; t < 8; ++t) {
    u16* bu = sm + (t & 1) * 16384;
    u16* bn = sm + ((t + 1) & 1) * 16384;
    if (t < 7) WLOAD((t + 1) * 64);
    const u16 *a_ = bu, *b_ = bu + 8192;
#pragma unroll
    for (int kk = 0; kk < 2; ++kk) {
      const int ko = kk ? ko1 : ko0;
      bf16x8 af[4], bf[2];
#pragma unroll
      for (int i = 0; i < 4; ++i) af[i] = *(const bf16x8*)(a_ + (wm + i * 16 + lm) * 64 + ko);
#pragma unroll
      for (int j = 0; j < 2; ++j) bf[j] = *(const bf16x8*)(b_ + (wn + j * 16 + lm) * 64 + ko);
      PRIO1();
#pragma unroll
      for (int i = 0; i < 4; ++i)
#pragma unroll
        for (int j = 0; j < 2; ++j)
          acc[i][j] = __builtin_amdgcn_mfma_f32_16x16x32_bf16(af[i], bf[j], acc[i][j], 0, 0, 0);
      PRIO0();
    }
    if (t < 7) { WAITV0(); WWRITE(bn); }
    LGKM0(); BAR(); SCB();
  }
  const int cr = (l >> 4) * 4, cc = lm;
#pragma unroll
  for (int i = 0; i < 4; ++i)
#pragma unroll
    for (int j = 0; j < 2; ++j)
#pragma unroll
      for (int r = 0; r < 4; ++r)
        hb[(size_t)(m0 + wm + i * 16 + cr + r) * HDIM + n0 + wn + j * 16 + cc] =
            f2bf(acc[i][j][r]);
}

// ---- outgemm: out = cb @ Wo^T, A bf16 g2l (pre-swizzled src), B fp32 reg-staged (r6) ----
__global__ __launch_bounds__(512, 2) void outgemm_kernel(
    const u16* __restrict__ cb, const float* __restrict__ Wo, float* __restrict__ out) {
  __shared__ __align__(16) u16 sm[32768];  // 64 KB
  const int m0 = blockIdx.y * 128, n0 = blockIdx.x * 128;
  const int tid = threadIdx.x, w = tid >> 6, l = tid & 63;
  const int wm = (w >> 2) * 64, wn = (w & 3) * 32;
  const int lm = l & 15, lk = (l >> 4) * 8, xr = (l & 7) * 8;
  const int lr = l >> 3, c8 = l & 7;
  const int ko0 = lk ^ xr, ko1 = (32 + lk) ^ xr;
  const int wcol = (c8 ^ lr) * 8;
  const u16* Ap0 = cb + (size_t)(m0 + w * 8 + lr) * HDIM + wcol;  // pre-swizzled src
  const u16* Ap1 = Ap0 + (size_t)64 * HDIM;
  const float* Bp0 = Wo + (size_t)(n0 + w * 8 + lr) * HDIM + c8 * 8;
  const float* Bp1 = Bp0 + (size_t)64 * HDIM;
  f32x4 acc[4][2] = {};
  float4 v4, v5, v6, v7;
  auto WLOADB = [&](int kt) {
    v4 = *(const float4*)(Bp0 + kt); v5 = *(const float4*)(Bp0 + kt + 4);
    v6 = *(const float4*)(Bp1 + kt); v7 = *(const float4*)(Bp1 + kt + 4);
  };
  auto WWRITEB = [&](u16* st) {
    *(int4*)(st + 8192 + (w * 8 + lr) * 64 + wcol) = pk8(v4, v5);
    *(int4*)(st + 8192 + (64 + w * 8 + lr) * 64 + wcol) = pk8(v6, v7);
  };
  auto STGA = [&](u16* st, int kt) {
    g2l16(Ap0 + kt, st + w * 512);
    g2l16(Ap1 + kt, st + 4096 + w * 512);
  };
  WLOADB(0); SCB(); STGA(sm, 0);
  WAITV2(); WWRITEB(sm);
  WAITV0(); LGKM0(); BAR(); SCB();
  for (int t = 0; t < 8; ++t) {
    u16* bu = sm + (t & 1) * 16384;
    u16* bn = sm + ((t + 1) & 1) * 16384;
    if (t < 7) { WLOADB((t + 1) * 64); SCB(); STGA(bn, (t + 1) * 64); }
    const u16 *a_ = bu, *b_ = bu + 8192;
#pragma unroll
    for (int kk = 0; kk < 2; ++kk) {
      const int ko = kk ? ko1 : ko0;
      bf16x8 af[4], bf[2];
#pragma unroll
      for (int i = 0; i < 4; ++i) af[i] = *(const bf16x8*)(a_ + (wm + i * 16 + lm) * 64 + ko);
#pragma unroll
      for (int j = 0; j < 2; ++j) bf[j] = *(const bf16x8*)(b_ + (wn + j * 16 + lm) * 64 + ko);
      PRIO1();
#pragma unroll
      for (int i = 0; i < 4; ++i)
#pragma unroll
        for (int j = 0; j < 2; ++j)
          acc[i][j] = __builtin_amdgcn_mfma_f32_16x16x32_bf16(af[i], bf[j], acc[i][j], 0, 0, 0);
      PRIO0();
    }
    if (t < 7) { WAITV2(); WWRITEB(bn); WAITV0(); }
    LGKM0(); BAR(); SCB();
  }
  const int cr = (l >> 4) * 4, cc = lm;
#pragma unroll
  for (int i = 0; i < 4; ++i)
#pragma unroll
    for (int j = 0; j < 2; ++j)
#pragma unroll
      for (int r = 0; r < 4; ++r)
        out[(size_t)(m0 + wm + i * 16 + cr + r) * HDIM + n0 + wn + j * 16 + cc] = acc[i][j][r];
}

// ---- gateup (measured-best, 55.3us): 128 rows x (128G+128U), bf16 weights via g2l,
// ---- 3-buffer counted-vmcnt pipeline, 144 KB LDS ----
__global__ __launch_bounds__(512, 2) void gateup_kernel(
    const u16* __restrict__ hb, const u16* __restrict__ Wg, const u16* __restrict__ Wu,
    u16* __restrict__ act, const int* __restrict__ tok, const int* __restrict__ rbe,
    const int* __restrict__ rbp, const int* __restrict__ nrb) {
  const int rb = blockIdx.y;
  if (rb >= nrb[0]) return;
  __shared__ __align__(16) u16 sm[73728];  // 144 KB: 3 x (A 16K | G 16K | U 16K bytes)
  const int e = rbe[rb], p0 = rbp[rb], n0 = blockIdx.x * 128;
  const int tid = threadIdx.x, w = tid >> 6, l = tid & 63;
  const int wm = (w >> 2) * 64, wn = (w & 3) * 32;
  const int lm = l & 15, lk = (l >> 4) * 8, xr = (l & 7) << 3;
  const int sr = l >> 3, sc = ((l & 7) ^ sr) * 8;
  const u16* A0 = hb + (size_t)tok[p0 + w * 8 + sr] * HDIM + sc;
  const u16* A1 = hb + (size_t)tok[p0 + 64 + w * 8 + sr] * HDIM + sc;
  const u16* G0 = Wg + (size_t)e * FDIM * HDIM + (size_t)(n0 + w * 8 + sr) * HDIM + sc;
  const u16* G1 = G0 + (size_t)64 * HDIM;
  const u16* U0 = Wu + (size_t)e * FDIM * HDIM + (size_t)(n0 + w * 8 + sr) * HDIM + sc;
  const u16* U1 = U0 + (size_t)64 * HDIM;
  f32x4 ag[4][2] = {}, au[4][2] = {};
  auto STG = [&](int b, int kt) {  // 6 vmem instrs
    u16* d = sm + b * 24576;
    g2l16(A0 + kt, d + w * 512);
    g2l16(A1 + kt, d + 4096 + w * 512);
    g2l16(G0 + kt, d + 8192 + w * 512);
    g2l16(G1 + kt, d + 12288 + w * 512);
    g2l16(U0 + kt, d + 16384 + w * 512);
    g2l16(U1 + kt, d + 20480 + w * 512);
  };
  auto CMP = [&](int b) {
    const u16* a_ = sm + b * 24576;
    const u16* g_ = a_ + 8192;
    const u16* u_ = a_ + 16384;
#pragma unroll
    for (int kk = 0; kk < 2; ++kk) {
      const int ko = (kk * 32 + lk) ^ xr;
      bf16x8 af[4], gf[2], uf[2];
#pragma unroll
      for (int i = 0; i < 4; ++i) af[i] = *(const bf16x8*)(a_ + (wm + i * 16 + lm) * 64 + ko);
#pragma unroll
      for (int j = 0; j < 2; ++j) {
        gf[j] = *(const bf16x8*)(g_ + (wn + j * 16 + lm) * 64 + ko);
        uf[j] = *(const bf16x8*)(u_ + (wn + j * 16 + lm) * 64 + ko);
      }
#pragma unroll
      for (int i = 0; i < 4; ++i)
#pragma unroll
        for (int j = 0; j < 2; ++j) {
          ag[i][j] = __builtin_amdgcn_mfma_f32_16x16x32_bf16(af[i], gf[j], ag[i][j], 0, 0, 0);
          au[i][j] = __builtin_amdgcn_mfma_f32_16x16x32_bf16(af[i], uf[j], au[i][j], 0, 0, 0);
        }
    }
  };
  STG(0, 0); STG(1, 64);
  WAITV6(); BAR();  // stage 0 landed; stage 1 in flight
#pragma unroll
  for (int t = 0; t < 8; ++t) {
    if (t + 2 < 8) STG((t + 2) % 3, (t + 2) * 64);  // issue-early
    CMP(t % 3);
    if (t + 2 < 8) WAITV6(); else WAITV0();  // stage t+1 complete; newest stays in flight
    BAR();
  }
  const int cr = (l >> 4) * 4, cc = lm;
#pragma unroll
  for (int i = 0; i < 4; ++i)
#pragma unroll
    for (int j = 0; j < 2; ++j)
#pragma unroll
      for (int r = 0; r < 4; ++r) {
        const float g = ag[i][j][r], u = au[i][j][r];
        const float s = g / (1.0f + __expf(-g));
        act[(size_t)(p0 + wm + i * 16 + cr + r) * FDIM + n0 + wn + j * 16 + cc] = f2bf(s * u);
      }
}

// ---- down (r2-config): 128x128, kk-split waves, 3-buffer pipeline, bf16 out ----
__global__ __launch_bounds__(512, 2) void down_kernel(
    const u16* __restrict__ act, const u16* __restrict__ Wd, u16* __restrict__ dwn,
    const int* __restrict__ rbe, const int* __restrict__ rbp, const int* __restrict__ nrb) {
  const int rb = blockIdx.y;
  if (rb >= nrb[0]) return;
  __shared__ __align__(16) u16 sm[49152];  // 96 KB: 3 x (A 16K | B 16K bytes)
  const int e = rbe[rb], p0 = rbp[rb], n0 = blockIdx.x * 128;
  const int tid = threadIdx.x, w = tid >> 6, l = tid & 63;
  const int g = w >> 2;                         // kk-group: 0 -> k0..31, 1 -> k32..63
  const int wm = ((w >> 1) & 1) * 64, wn = (w & 1) * 64;
  const int lm = l & 15, lk = (l >> 4) * 8, xr = (l & 7) << 3;
  const int ko = (g * 32 + lk) ^ xr;
  const int sr = l >> 3, sc = ((l & 7) ^ sr) * 8;
  const u16* As = act + (size_t)(p0 + w * 8 + sr) * FDIM + sc;
  const u16* Bs = Wd + (size_t)e * HDIM * FDIM + (size_t)(n0 + w * 8 + sr) * FDIM + sc;
  f32x4 acc[4][4] = {};
  auto STG = [&](int b, int kt) {  // 4 vmem instrs
    u16* d = sm + b * 16384;
    g2l16(As + kt, d + w * 512);
    g2l16(As + (size_t)64 * FDIM + kt, d + 4096 + w * 512);
    g2l16(Bs + kt, d + 8192 + w * 512);
    g2l16(Bs + (size_t)64 * FDIM + kt, d + 12288 + w * 512);
  };
  auto CMP = [&](int b) {
    const u16* a_ = sm + b * 16384;
    const u16* b_ = a_ + 8192;
    bf16x8 af[4], bf[4];
#pragma unroll
    for (int i = 0; i < 4; ++i) af[i] = *(const bf16x8*)(a_ + (wm + i * 16 + lm) * 64 + ko);
#pragma unroll
    for (int j = 0; j < 4; ++j) bf[j] = *(const bf16x8*)(b_ + (wn + j * 16 + lm) * 64 + ko);
#pragma unroll
    for (int i = 0; i < 4; ++i)
#pragma unroll
      for (int j = 0; j < 4; ++j)
        acc[i][j] = __builtin_amdgcn_mfma_f32_16x16x32_bf16(af[i], bf[j], acc[i][j], 0, 0, 0);
  };
  STG(0, 0); STG(1, 64);
  WAITV4(); BAR();
#pragma unroll
  for (int t = 0; t < 32; ++t) {
    if (t + 2 < 32) STG((t + 2) % 3, (t + 2) * 64);
    CMP(t % 3);
    if (t + 2 < 32) WAITV4(); else WAITV0();
    BAR();
  }
  // partner-wave reduction: waves 4-7 (kk=1) dump partials; waves 0-3 add + store
  LGKM0();
  SCB();
  BAR();
  float* red = (float*)sm;
  if (g == 1) {
#pragma unroll
    for (int i = 0; i < 4; ++i)
#pragma unroll
      for (int j = 0; j < 4; ++j)
        *(f32x4*)&red[(w & 3) * 4096 + (i * 4 + j) * 256 + l * 4] = acc[i][j];
  }
  BAR();
  if (g == 0) {
    const int cr = (l >> 4) * 4, cc = lm;
#pragma unroll
    for (int i = 0; i < 4; ++i)
#pragma unroll
      for (int j = 0; j < 4; ++j) {
        const f32x4 o = *(const f32x4*)&red[w * 4096 + (i * 4 + j) * 256 + l * 4];
        const f32x4 s = acc[i][j] + o;
#pragma unroll
        for (int r = 0; r < 4; ++r)
          dwn[(size_t)(p0 + wm + i * 16 + cr + r) * HDIM + n0 + wn + j * 16 + cc] = f2bf(s[r]);
      }
  }
}

// ---------------- combine: c[n] = w0*down[pos0] + w1*down[pos1] (bf16 in/out) ----------------
__global__ void combine_kernel(const u16* __restrict__ dwn, const int* __restrict__ pos,
                               const float* __restrict__ wts, u16* __restrict__ cb) {
  const int n = blockIdx.x, t = threadIdx.x;  // 128 threads x 4 elems
  const int p0 = pos[2 * n], p1 = pos[2 * n + 1];
  const float w0 = wts[2 * n], w1 = wts[2 * n + 1];
  const ushort4 a = ((const ushort4*)(dwn + (size_t)p0 * HDIM))[t];
  const ushort4 b = ((const ushort4*)(dwn + (size_t)p1 * HDIM))[t];
  ushort4 o;
  o.x = f2bf(w0 * bf2f(a.x) + w1 * bf2f(b.x));
  o.y = f2bf(w0 * bf2f(a.y) + w1 * bf2f(b.y));
  o.z = f2bf(w0 * bf2f(a.z) + w1 * bf2f(b.z));
  o.w = f2bf(w0 * bf2f(a.w) + w1 * bf2f(b.w));
  ((ushort4*)(cb + (size_t)n * HDIM))[t] = o;
}

extern "C" void kernel_launch(void* const* d_in, const int* in_sizes, int n_in,
                              void* d_out, int out_size, void* d_ws, size_t ws_size,
                              hipStream_t stream) {
  const float* x  = (const float*)d_in[0];
  const float* Wi = (const float*)d_in[1];
  const float* Wr = (const float*)d_in[2];
  const float* Wg = (const float*)d_in[3];
  const float* Wu = (const float*)d_in[4];
  const float* Wd = (const float*)d_in[5];
  const float* Wo = (const float*)d_in[6];
  float* out = (float*)d_out;

  char* ws = (char*)d_ws;
  size_t off = 0;
  auto alloc = [&](size_t bytes) -> void* {
    off = (off + 255) & ~(size_t)255;
    void* p = ws + off;
    off += bytes;
    return p;
  };
  u16* hb   = (u16*)alloc((size_t)NTOK * HDIM * 2);
  u16* cb   = (u16*)alloc((size_t)NTOK * HDIM * 2);
  u16* Wgb  = (u16*)alloc((size_t)NEXP * FDIM * HDIM * 2);
  u16* Wub  = (u16*)alloc((size_t)NEXP * FDIM * HDIM * 2);
  u16* Wdb  = (u16*)alloc((size_t)NEXP * HDIM * FDIM * 2);
  u16* actb = (u16*)alloc((size_t)NPAD * FDIM * 2);
  u16* dwn  = (u16*)alloc((size_t)NPAD * HDIM * 2);
  double* wre = (double*)alloc((size_t)NEXP * HDIM * 8);
  int* idx = (int*)alloc((size_t)NASSIGN * 4);
  float* wts = (float*)alloc((size_t)NASSIGN * 4);
  int* tok = (int*)alloc((size_t)NPAD * 4);
  int* pos = (int*)alloc((size_t)NASSIGN * 4);
  int* rbe = (int*)alloc((size_t)RBMAX * 4);
  int* rbp = (int*)alloc((size_t)RBMAX * 4);
  int* nrb = (int*)alloc(256);

  cvtw_kernel<<<2048, 256, 0, stream>>>(Wg, Wu, Wd, Wgb, Wub, Wdb);
  wreff_kernel<<<16, 256, 0, stream>>>(Wr, Wi, wre);
  router_kernel<<<32, 128, 0, stream>>>(x, wre, idx, wts);
  assign_kernel<<<1, 256, 0, stream>>>(idx, tok, pos, rbe, rbp, nrb);
  ingemm_kernel<<<dim3(4, 32), 512, 0, stream>>>(x, Wi, hb);
  gateup_kernel<<<dim3(16, 72), 512, 0, stream>>>(hb, Wgb, Wub, actb, tok, rbe, rbp, nrb);
  down_kernel<<<dim3(4, 72), 512, 0, stream>>>(actb, Wdb, dwn, rbe, rbp, nrb);
  combine_kernel<<<NTOK, 128, 0, stream>>>(dwn, pos, wts, cb);
  outgemm_kernel<<<dim3(4, 32), 512, 0, stream>>>(cb, Wo, out);
}

// Round 8
// 226.630 us; speedup vs baseline: 1.1883x; 1.0294x over previous
//
#include <hip/hip_runtime.h>
#include <hip/hip_bf16.h>

typedef unsigned short u16;
typedef unsigned int u32;
typedef short bf16x8 __attribute__((ext_vector_type(8)));
typedef float f32x4 __attribute__((ext_vector_type(4)));

#define AS1 __attribute__((address_space(1)))
#define AS3 __attribute__((address_space(3)))

#define NTOK 4096
#define HDIM 512
#define FDIM 2048
#define NEXP 8
#define NASSIGN (NTOK * 2)
#define NPAD (NASSIGN + NEXP * 128)  // 9216
#define RBMAX 128

__device__ __forceinline__ void g2l16(const void* g, void* l) {
  __builtin_amdgcn_global_load_lds((const AS1 u32*)g, (AS3 u32*)l, 16, 0, 0);
}
__device__ __forceinline__ u16 f2bf(float f) {  // RNE fp32->bf16
  u32 u = __float_as_uint(f);
  u = (u + 0x7FFFu + ((u >> 16) & 1u)) >> 16;
  return (u16)u;
}
__device__ __forceinline__ float bf2f(u16 h) { return __uint_as_float(((u32)h) << 16); }
__device__ __forceinline__ u32 pkbf(float a, float b) {  // v_cvt_pk_bf16_f32 (RNE)
  __hip_bfloat162 h = __float22bfloat162_rn(float2{a, b});
  u32 r;
  __builtin_memcpy(&r, &h, 4);
  return r;
}
__device__ __forceinline__ int4 pk8(const float4 a, const float4 b) {
  int4 r;
  r.x = (int)pkbf(a.x, a.y); r.y = (int)pkbf(a.z, a.w);
  r.z = (int)pkbf(b.x, b.y); r.w = (int)pkbf(b.z, b.w);
  return r;
}

#define WAITV6() asm volatile("s_waitcnt vmcnt(6)" ::: "memory")
#define WAITV4() asm volatile("s_waitcnt vmcnt(4)" ::: "memory")
#define WAITV2() asm volatile("s_waitcnt vmcnt(2)" ::: "memory")
#define WAITV0() asm volatile("s_waitcnt vmcnt(0)" ::: "memory")
#define LGKM0() asm volatile("s_waitcnt lgkmcnt(0)" ::: "memory")
#define BAR() __builtin_amdgcn_s_barrier()
#define SCB() __builtin_amdgcn_sched_barrier(0)
#define PRIO1() __builtin_amdgcn_s_setprio(1)
#define PRIO0() __builtin_amdgcn_s_setprio(0)
#define VMBAR() do { WAITV0(); BAR(); } while (0)

// ---- cvtall: fp32->bf16 for x/Wi/Wo/Wg/Wu/Wd. Block = contiguous 16384-float chunk.
// ---- 16 batched float4 loads/thread (256B in flight), 8 x 16B stores. 1696 chunks:
// ---- x [0,128) | Wi [128,144) | Wo [144,160) | Wg [160,672) | Wu [672,1184) | Wd [1184,1696)
__global__ __launch_bounds__(256) void cvtall_kernel(
    const float* __restrict__ x, const float* __restrict__ Wi, const float* __restrict__ Wo,
    const float* __restrict__ Wg, const float* __restrict__ Wu, const float* __restrict__ Wd,
    u16* __restrict__ xb, u16* __restrict__ Wib, u16* __restrict__ Wob,
    u16* __restrict__ Wgb, u16* __restrict__ Wub, u16* __restrict__ Wdb) {
  const int c = blockIdx.x, tid = threadIdx.x;
  const float* s; u16* d; int cs;
  if (c < 128) { s = x; d = xb; cs = 0; }
  else if (c < 144) { s = Wi; d = Wib; cs = 128; }
  else if (c < 160) { s = Wo; d = Wob; cs = 144; }
  else if (c < 672) { s = Wg; d = Wgb; cs = 160; }
  else if (c < 1184) { s = Wu; d = Wub; cs = 672; }
  else { s = Wd; d = Wdb; cs = 1184; }
  const size_t base = (size_t)(c - cs) * 16384 + (size_t)tid * 8;
  const float* sp = s + base;
  u16* dp = d + base;
  float4 a[16];
#pragma unroll
  for (int j = 0; j < 8; ++j) {
    a[2 * j] = *(const float4*)(sp + j * 2048);
    a[2 * j + 1] = *(const float4*)(sp + j * 2048 + 4);
  }
#pragma unroll
  for (int j = 0; j < 8; ++j)
    *(int4*)(dp + j * 2048) = pk8(a[2 * j], a[2 * j + 1]);
}

// ---------------- Wr_eff = W_router @ W_in (fp64, exact routing) ----------------
__global__ __launch_bounds__(256) void wreff_kernel(
    const float* __restrict__ Wr, const float* __restrict__ Wi, double* __restrict__ wre) {
  const int t = blockIdx.x * 256 + threadIdx.x;  // e*512+k
  const int e = t >> 9, k = t & 511;
  const float* wr = Wr + e * HDIM;
  double a0 = 0.0, a1 = 0.0, a2 = 0.0, a3 = 0.0;
  for (int j = 0; j < HDIM; j += 4) {
    a0 += (double)wr[j + 0] * (double)Wi[(j + 0) * HDIM + k];
    a1 += (double)wr[j + 1] * (double)Wi[(j + 1) * HDIM + k];
    a2 += (double)wr[j + 2] * (double)Wi[(j + 2) * HDIM + k];
    a3 += (double)wr[j + 3] * (double)Wi[(j + 3) * HDIM + k];
  }
  wre[t] = (a0 + a1) + (a2 + a3);
}

// ---------------- router: logits = x @ Wr_eff^T (fp64), softmax, top-2 ----------------
__global__ __launch_bounds__(128) void router_kernel(
    const float* __restrict__ x, const double* __restrict__ wre,
    int* __restrict__ idx, float* __restrict__ wts) {
  __shared__ double lw[NEXP * HDIM];  // 32 KB
  for (int i = threadIdx.x; i < NEXP * HDIM; i += 128) lw[i] = wre[i];
  __syncthreads();
  const int n = blockIdx.x * 128 + threadIdx.x;
  const float* xr = x + (size_t)n * HDIM;
  double acc[NEXP] = {};
  for (int k4 = 0; k4 < HDIM / 4; ++k4) {
    const float4 xv = ((const float4*)xr)[k4];
    const float xc[4] = {xv.x, xv.y, xv.z, xv.w};
#pragma unroll
    for (int c = 0; c < 4; ++c) {
      const double xd = (double)xc[c];
#pragma unroll
      for (int e = 0; e < NEXP; ++e) acc[e] += xd * lw[e * HDIM + k4 * 4 + c];
    }
  }
  double mx = acc[0];
#pragma unroll
  for (int e = 1; e < NEXP; ++e) mx = acc[e] > mx ? acc[e] : mx;
  double p[NEXP], se = 0.0;
#pragma unroll
  for (int e = 0; e < NEXP; ++e) { p[e] = exp(acc[e] - mx); se += p[e]; }
  const double inv = 1.0 / se;
#pragma unroll
  for (int e = 0; e < NEXP; ++e) p[e] *= inv;
  int i0 = 0; double b0 = p[0];
#pragma unroll
  for (int e = 1; e < NEXP; ++e) if (p[e] > b0) { b0 = p[e]; i0 = e; }
  int i1 = -1; double b1 = -1.0;
#pragma unroll
  for (int e = 0; e < NEXP; ++e) if (e != i0 && p[e] > b1) { b1 = p[e]; i1 = e; }
  const double e0 = exp(b0), e1 = exp(b1);  // softmax OF the top-2 probabilities
  idx[2 * n] = i0; idx[2 * n + 1] = i1;
  wts[2 * n] = (float)(e0 / (e0 + e1));
  wts[2 * n + 1] = (float)(e1 / (e0 + e1));
}

// ---------------- gather lists + 128-padded rowblock schedule ----------------
__global__ void assign_kernel(const int* __restrict__ idx, int* __restrict__ tok,
                              int* __restrict__ pos, int* __restrict__ rbe,
                              int* __restrict__ rbp, int* __restrict__ nrb) {
  __shared__ int cnt[NEXP], cur[NEXP];
  const int tid = threadIdx.x;
  if (tid < NEXP) cnt[tid] = 0;
  __syncthreads();
  for (int a = tid; a < NASSIGN; a += 256) atomicAdd(&cnt[idx[a]], 1);
  __syncthreads();
  if (tid == 0) {
    int o = 0, n = 0;
    for (int e = 0; e < NEXP; ++e) {
      cur[e] = o;
      const int nb = (cnt[e] + 127) >> 7;
      for (int i = 0; i < nb; ++i) { rbe[n] = e; rbp[n] = o + i * 128; ++n; }
      o += nb * 128;
    }
    nrb[0] = n;
  }
  __syncthreads();
  for (int p = tid; p < NPAD; p += 256) tok[p] = 0;  // pad rows -> token 0 (never read back)
  __syncthreads();
  for (int a = tid; a < NASSIGN; a += 256) {
    const int e = idx[a];
    const int q = atomicAdd(&cur[e], 1);
    tok[q] = a >> 1;
    pos[a] = q;
  }
}

// ---------------- 128x128 BT GEMM body (r3-proven: 2-phase dbuf, swizzled g2l) ----------------
template <int SB, int NT>
__device__ __forceinline__ void gemm128_body(
    const u16* __restrict__ A, const u16* __restrict__ B, void* __restrict__ C,
    int m0, int n0, int N, int K, u16* sm, int tid) {
  u16 *lA0 = sm, *lA1 = sm + 8192, *lB0 = sm + 16384, *lB1 = sm + 24576;
  const int w = tid >> 6, l = tid & 63;
  const int wm = (w >> 2) * 64, wn = (w & 3) * 32;
  const int lm = l & 15, lk = (l >> 4) * 8, xr = (l & 7) << 3;
  const int sr = l >> 3, sc = ((l & 7) ^ sr) * 8;
  const u16* As = A + (size_t)(m0 + w * 8 + sr) * K + sc;
  const u16* Bs = B + (size_t)(n0 + w * 8 + sr) * K + sc;
  f32x4 acc[4][2] = {};
  auto STG = [&](u16* dA, u16* dB, int kt) {
    g2l16(As + kt, dA + w * 512);
    g2l16(As + (size_t)64 * K + kt, dA + 4096 + w * 512);
    g2l16(Bs + kt, dB + w * 512);
    g2l16(Bs + (size_t)64 * K + kt, dB + 4096 + w * 512);
  };
  auto CMP = [&](const u16* a_, const u16* b_) {
#pragma unroll
    for (int kk = 0; kk < 2; ++kk) {
      const int ko = (kk * 32 + lk) ^ xr;
      bf16x8 af[4], bf[2];
#pragma unroll
      for (int i = 0; i < 4; ++i) af[i] = *(const bf16x8*)(a_ + (wm + i * 16 + lm) * 64 + ko);
#pragma unroll
      for (int j = 0; j < 2; ++j) bf[j] = *(const bf16x8*)(b_ + (wn + j * 16 + lm) * 64 + ko);
      PRIO1();
#pragma unroll
      for (int i = 0; i < 4; ++i)
#pragma unroll
        for (int j = 0; j < 2; ++j)
          acc[i][j] = __builtin_amdgcn_mfma_f32_16x16x32_bf16(af[i], bf[j], acc[i][j], 0, 0, 0);
      PRIO0();
    }
  };
  STG(lA0, lB0, 0);
  VMBAR();
  for (int t = 0; t < NT; t += 2) {
    if (t + 1 < NT) STG(lA1, lB1, (t + 1) * 64);
    CMP(lA0, lB0);
    VMBAR();
    if (t + 2 < NT) STG(lA0, lB0, (t + 2) * 64);
    CMP(lA1, lB1);
    VMBAR();
  }
  const int cr = (l >> 4) * 4, cc = lm;
#pragma unroll
  for (int i = 0; i < 4; ++i)
#pragma unroll
    for (int j = 0; j < 2; ++j)
#pragma unroll
      for (int r = 0; r < 4; ++r) {
        const size_t o = (size_t)(m0 + wm + i * 16 + cr + r) * N + n0 + wn + j * 16 + cc;
        if (SB) ((u16*)C)[o] = f2bf(acc[i][j][r]);
        else ((float*)C)[o] = acc[i][j][r];
      }
}

__global__ __launch_bounds__(512, 2) void ingemm_kernel(
    const u16* __restrict__ xb, const u16* __restrict__ Wib, u16* __restrict__ hb) {
  __shared__ __align__(16) u16 sm[32768];  // 64 KB
  gemm128_body<1, 8>(xb, Wib, hb, blockIdx.y * 128, blockIdx.x * 128, HDIM, HDIM, sm, threadIdx.x);
}

// ---- outgemm + fused combine: A[row] = w0*dwn[pos0] + w1*dwn[pos1] (reg blend -> swz ds_write),
// ---- B = Wob bf16 via g2l (pre-swizzled source). fp32 out. ----
__global__ __launch_bounds__(512, 2) void outgemm_kernel(
    const u16* __restrict__ dwn, const u16* __restrict__ Wob, const int* __restrict__ pos,
    const float* __restrict__ wts, float* __restrict__ out) {
  __shared__ __align__(16) u16 sm[32768];  // 64 KB: 2 x (A[128][64] | B[128][64])
  const int m0 = blockIdx.y * 128, n0 = blockIdx.x * 128;
  const int tid = threadIdx.x, w = tid >> 6, l = tid & 63;
  const int wm = (w >> 2) * 64, wn = (w & 3) * 32;
  const int lm = l & 15, lk = (l >> 4) * 8, xr = (l & 7) << 3;
  const int lr = l >> 3, c8 = l & 7;
  const int sc = (c8 ^ lr) * 8;  // swizzled col: B source pre-swz, A ds_write dest
  // this thread's two A rows (tokens) and their routing
  const int t0 = m0 + w * 8 + lr, t1 = t0 + 64;
  const int p00 = pos[2 * t0], p01 = pos[2 * t0 + 1];
  const int p10 = pos[2 * t1], p11 = pos[2 * t1 + 1];
  const float w00 = wts[2 * t0], w01 = wts[2 * t0 + 1];
  const float w10 = wts[2 * t1], w11 = wts[2 * t1 + 1];
  const u16* A00 = dwn + (size_t)p00 * HDIM + c8 * 8;
  const u16* A01 = dwn + (size_t)p01 * HDIM + c8 * 8;
  const u16* A10 = dwn + (size_t)p10 * HDIM + c8 * 8;
  const u16* A11 = dwn + (size_t)p11 * HDIM + c8 * 8;
  const u16* Bs = Wob + (size_t)(n0 + w * 8 + lr) * HDIM + sc;
  f32x4 acc[4][2] = {};
  bf16x8 a00, a01, a10, a11;
  auto ALOAD = [&](int kt) {  // 4 x 16B global loads
    a00 = *(const bf16x8*)(A00 + kt); a01 = *(const bf16x8*)(A01 + kt);
    a10 = *(const bf16x8*)(A10 + kt); a11 = *(const bf16x8*)(A11 + kt);
  };
  auto AWRITE = [&](u16* st) {  // blend + swizzled ds_write (combine fused)
    bf16x8 r0, r1;
#pragma unroll
    for (int q = 0; q < 8; ++q) {
      r0[q] = (short)f2bf(w00 * bf2f((u16)a00[q]) + w01 * bf2f((u16)a01[q]));
      r1[q] = (short)f2bf(w10 * bf2f((u16)a10[q]) + w11 * bf2f((u16)a11[q]));
    }
    *(bf16x8*)(st + (w * 8 + lr) * 64 + sc) = r0;
    *(bf16x8*)(st + (64 + w * 8 + lr) * 64 + sc) = r1;
  };
  auto STGB = [&](u16* st, int kt) {  // 2 g2l16
    g2l16(Bs + kt, st + 8192 + w * 512);
    g2l16(Bs + (size_t)64 * HDIM + kt, st + 8192 + 4096 + w * 512);
  };
  auto CMP = [&](const u16* a_, const u16* b_) {
#pragma unroll
    for (int kk = 0; kk < 2; ++kk) {
      const int ko = (kk * 32 + lk) ^ xr;
      bf16x8 af[4], bf[2];
#pragma unroll
      for (int i = 0; i < 4; ++i) af[i] = *(const bf16x8*)(a_ + (wm + i * 16 + lm) * 64 + ko);
#pragma unroll
      for (int j = 0; j < 2; ++j) bf[j] = *(const bf16x8*)(b_ + (wn + j * 16 + lm) * 64 + ko);
      PRIO1();
#pragma unroll
      for (int i = 0; i < 4; ++i)
#pragma unroll
        for (int j = 0; j < 2; ++j)
          acc[i][j] = __builtin_amdgcn_mfma_f32_16x16x32_bf16(af[i], bf[j], acc[i][j], 0, 0, 0);
      PRIO0();
    }
  };
  ALOAD(0); SCB(); STGB(sm, 0);
  WAITV2(); AWRITE(sm);        // 4 A loads landed; 2 B g2l outstanding
  WAITV0(); LGKM0(); BAR(); SCB();
  for (int t = 0; t < 8; ++t) {
    u16* bu = sm + (t & 1) * 16384;
    u16* bn = sm + ((t + 1) & 1) * 16384;
    if (t < 7) { ALOAD((t + 1) * 64); SCB(); STGB(bn, (t + 1) * 64); }
    CMP(bu, bu + 8192);
    if (t < 7) { WAITV2(); AWRITE(bn); WAITV0(); }
    LGKM0(); BAR(); SCB();
  }
  const int cr = (l >> 4) * 4, cc = lm;
#pragma unroll
  for (int i = 0; i < 4; ++i)
#pragma unroll
    for (int j = 0; j < 2; ++j)
#pragma unroll
      for (int r = 0; r < 4; ++r)
        out[(size_t)(m0 + wm + i * 16 + cr + r) * HDIM + n0 + wn + j * 16 + cc] = acc[i][j][r];
}

// ---- gateup (measured-best 55-56us): 128 rows x (128G+128U), bf16 via g2l,
// ---- 3-buffer counted-vmcnt pipeline, 144 KB LDS ----
__global__ __launch_bounds__(512, 2) void gateup_kernel(
    const u16* __restrict__ hb, const u16* __restrict__ Wg, const u16* __restrict__ Wu,
    u16* __restrict__ act, const int* __restrict__ tok, const int* __restrict__ rbe,
    const int* __restrict__ rbp, const int* __restrict__ nrb) {
  const int rb = blockIdx.y;
  if (rb >= nrb[0]) return;
  __shared__ __align__(16) u16 sm[73728];  // 144 KB: 3 x (A 16K | G 16K | U 16K bytes)
  const int e = rbe[rb], p0 = rbp[rb], n0 = blockIdx.x * 128;
  const int tid = threadIdx.x, w = tid >> 6, l = tid & 63;
  const int wm = (w >> 2) * 64, wn = (w & 3) * 32;
  const int lm = l & 15, lk = (l >> 4) * 8, xr = (l & 7) << 3;
  const int sr = l >> 3, sc = ((l & 7) ^ sr) * 8;
  const u16* A0 = hb + (size_t)tok[p0 + w * 8 + sr] * HDIM + sc;
  const u16* A1 = hb + (size_t)tok[p0 + 64 + w * 8 + sr] * HDIM + sc;
  const u16* G0 = Wg + (size_t)e * FDIM * HDIM + (size_t)(n0 + w * 8 + sr) * HDIM + sc;
  const u16* G1 = G0 + (size_t)64 * HDIM;
  const u16* U0 = Wu + (size_t)e * FDIM * HDIM + (size_t)(n0 + w * 8 + sr) * HDIM + sc;
  const u16* U1 = U0 + (size_t)64 * HDIM;
  f32x4 ag[4][2] = {}, au[4][2] = {};
  auto STG = [&](int b, int kt) {  // 6 vmem instrs
    u16* d = sm + b * 24576;
    g2l16(A0 + kt, d + w * 512);
    g2l16(A1 + kt, d + 4096 + w * 512);
    g2l16(G0 + kt, d + 8192 + w * 512);
    g2l16(G1 + kt, d + 12288 + w * 512);
    g2l16(U0 + kt, d + 16384 + w * 512);
    g2l16(U1 + kt, d + 20480 + w * 512);
  };
  auto CMP = [&](int b) {
    const u16* a_ = sm + b * 24576;
    const u16* g_ = a_ + 8192;
    const u16* u_ = a_ + 16384;
#pragma unroll
    for (int kk = 0; kk < 2; ++kk) {
      const int ko = (kk * 32 + lk) ^ xr;
      bf16x8 af[4], gf[2], uf[2];
#pragma unroll
      for (int i = 0; i < 4; ++i) af[i] = *(const bf16x8*)(a_ + (wm + i * 16 + lm) * 64 + ko);
#pragma unroll
      for (int j = 0; j < 2; ++j) {
        gf[j] = *(const bf16x8*)(g_ + (wn + j * 16 + lm) * 64 + ko);
        uf[j] = *(const bf16x8*)(u_ + (wn + j * 16 + lm) * 64 + ko);
      }
#pragma unroll
      for (int i = 0; i < 4; ++i)
#pragma unroll
        for (int j = 0; j < 2; ++j) {
          ag[i][j] = __builtin_amdgcn_mfma_f32_16x16x32_bf16(af[i], gf[j], ag[i][j], 0, 0, 0);
          au[i][j] = __builtin_amdgcn_mfma_f32_16x16x32_bf16(af[i], uf[j], au[i][j], 0, 0, 0);
        }
    }
  };
  STG(0, 0); STG(1, 64);
  WAITV6(); BAR();  // stage 0 landed; stage 1 in flight
#pragma unroll
  for (int t = 0; t < 8; ++t) {
    if (t + 2 < 8) STG((t + 2) % 3, (t + 2) * 64);  // issue-early
    CMP(t % 3);
    if (t + 2 < 8) WAITV6(); else WAITV0();  // stage t+1 complete; newest stays in flight
    BAR();
  }
  const int cr = (l >> 4) * 4, cc = lm;
#pragma unroll
  for (int i = 0; i < 4; ++i)
#pragma unroll
    for (int j = 0; j < 2; ++j)
#pragma unroll
      for (int r = 0; r < 4; ++r) {
        const float g = ag[i][j][r], u = au[i][j][r];
        const float s = g / (1.0f + __expf(-g));
        act[(size_t)(p0 + wm + i * 16 + cr + r) * FDIM + n0 + wn + j * 16 + cc] = f2bf(s * u);
      }
}

// ---- down (r2-config): 128x128, kk-split waves, 3-buffer pipeline, bf16 out ----
__global__ __launch_bounds__(512, 2) void down_kernel(
    const u16* __restrict__ act, const u16* __restrict__ Wd, u16* __restrict__ dwn,
    const int* __restrict__ rbe, const int* __restrict__ rbp, const int* __restrict__ nrb) {
  const int rb = blockIdx.y;
  if (rb >= nrb[0]) return;
  __shared__ __align__(16) u16 sm[49152];  // 96 KB: 3 x (A 16K | B 16K bytes)
  const int e = rbe[rb], p0 = rbp[rb], n0 = blockIdx.x * 128;
  const int tid = threadIdx.x, w = tid >> 6, l = tid & 63;
  const int g = w >> 2;                         // kk-group: 0 -> k0..31, 1 -> k32..63
  const int wm = ((w >> 1) & 1) * 64, wn = (w & 1) * 64;
  const int lm = l & 15, lk = (l >> 4) * 8, xr = (l & 7) << 3;
  const int ko = (g * 32 + lk) ^ xr;
  const int sr = l >> 3, sc = ((l & 7) ^ sr) * 8;
  const u16* As = act + (size_t)(p0 + w * 8 + sr) * FDIM + sc;
  const u16* Bs = Wd + (size_t)e * HDIM * FDIM + (size_t)(n0 + w * 8 + sr) * FDIM + sc;
  f32x4 acc[4][4] = {};
  auto STG = [&](int b, int kt) {  // 4 vmem instrs
    u16* d = sm + b * 16384;
    g2l16(As + kt, d + w * 512);
    g2l16(As + (size_t)64 * FDIM + kt, d + 4096 + w * 512);
    g2l16(Bs + kt, d + 8192 + w * 512);
    g2l16(Bs + (size_t)64 * FDIM + kt, d + 12288 + w * 512);
  };
  auto CMP = [&](int b) {
    const u16* a_ = sm + b * 16384;
    const u16* b_ = a_ + 8192;
    bf16x8 af[4], bf[4];
#pragma unroll
    for (int i = 0; i < 4; ++i) af[i] = *(const bf16x8*)(a_ + (wm + i * 16 + lm) * 64 + ko);
#pragma unroll
    for (int j = 0; j < 4; ++j) bf[j] = *(const bf16x8*)(b_ + (wn + j * 16 + lm) * 64 + ko);
#pragma unroll
    for (int i = 0; i < 4; ++i)
#pragma unroll
      for (int j = 0; j < 4; ++j)
        acc[i][j] = __builtin_amdgcn_mfma_f32_16x16x32_bf16(af[i], bf[j], acc[i][j], 0, 0, 0);
  };
  STG(0, 0); STG(1, 64);
  WAITV4(); BAR();
#pragma unroll
  for (int t = 0; t < 32; ++t) {
    if (t + 2 < 32) STG((t + 2) % 3, (t + 2) * 64);
    CMP(t % 3);
    if (t + 2 < 32) WAITV4(); else WAITV0();
    BAR();
  }
  // partner-wave reduction: waves 4-7 (kk=1) dump partials; waves 0-3 add + store
  LGKM0();
  SCB();
  BAR();
  float* red = (float*)sm;
  if (g == 1) {
#pragma unroll
    for (int i = 0; i < 4; ++i)
#pragma unroll
      for (int j = 0; j < 4; ++j)
        *(f32x4*)&red[(w & 3) * 4096 + (i * 4 + j) * 256 + l * 4] = acc[i][j];
  }
  BAR();
  if (g == 0) {
    const int cr = (l >> 4) * 4, cc = lm;
#pragma unroll
    for (int i = 0; i < 4; ++i)
#pragma unroll
      for (int j = 0; j < 4; ++j) {
        const f32x4 o = *(const f32x4*)&red[w * 4096 + (i * 4 + j) * 256 + l * 4];
        const f32x4 s = acc[i][j] + o;
#pragma unroll
        for (int r = 0; r < 4; ++r)
          dwn[(size_t)(p0 + wm + i * 16 + cr + r) * HDIM + n0 + wn + j * 16 + cc] = f2bf(s[r]);
      }
  }
}

extern "C" void kernel_launch(void* const* d_in, const int* in_sizes, int n_in,
                              void* d_out, int out_size, void* d_ws, size_t ws_size,
                              hipStream_t stream) {
  const float* x  = (const float*)d_in[0];
  const float* Wi = (const float*)d_in[1];
  const float* Wr = (const float*)d_in[2];
  const float* Wg = (const float*)d_in[3];
  const float* Wu = (const float*)d_in[4];
  const float* Wd = (const float*)d_in[5];
  const float* Wo = (const float*)d_in[6];
  float* out = (float*)d_out;

  char* ws = (char*)d_ws;
  size_t off = 0;
  auto alloc = [&](size_t bytes) -> void* {
    off = (off + 255) & ~(size_t)255;
    void* p = ws + off;
    off += bytes;
    return p;
  };
  u16* xb   = (u16*)alloc((size_t)NTOK * HDIM * 2);
  u16* hb   = (u16*)alloc((size_t)NTOK * HDIM * 2);
  u16* Wib  = (u16*)alloc((size_t)HDIM * HDIM * 2);
  u16* Wob  = (u16*)alloc((size_t)HDIM * HDIM * 2);
  u16* Wgb  = (u16*)alloc((size_t)NEXP * FDIM * HDIM * 2);
  u16* Wub  = (u16*)alloc((size_t)NEXP * FDIM * HDIM * 2);
  u16* Wdb  = (u16*)alloc((size_t)NEXP * HDIM * FDIM * 2);
  u16* actb = (u16*)alloc((size_t)NPAD * FDIM * 2);
  u16* dwn  = (u16*)alloc((size_t)NPAD * HDIM * 2);
  double* wre = (double*)alloc((size_t)NEXP * HDIM * 8);
  int* idx = (int*)alloc((size_t)NASSIGN * 4);
  float* wts = (float*)alloc((size_t)NASSIGN * 4);
  int* tok = (int*)alloc((size_t)NPAD * 4);
  int* pos = (int*)alloc((size_t)NASSIGN * 4);
  int* rbe = (int*)alloc((size_t)RBMAX * 4);
  int* rbp = (int*)alloc((size_t)RBMAX * 4);
  int* nrb = (int*)alloc(256);

  cvtall_kernel<<<1696, 256, 0, stream>>>(x, Wi, Wo, Wg, Wu, Wd, xb, Wib, Wob, Wgb, Wub, Wdb);
  wreff_kernel<<<16, 256, 0, stream>>>(Wr, Wi, wre);
  router_kernel<<<32, 128, 0, stream>>>(x, wre, idx, wts);
  assign_kernel<<<1, 256, 0, stream>>>(idx, tok, pos, rbe, rbp, nrb);
  ingemm_kernel<<<dim3(4, 32), 512, 0, stream>>>(xb, Wib, hb);
  gateup_kernel<<<dim3(16, 72), 512, 0, stream>>>(hb, Wgb, Wub, actb, tok, rbe, rbp, nrb);
  down_kernel<<<dim3(4, 72), 512, 0, stream>>>(actb, Wdb, dwn, rbe, rbp, nrb);
  outgemm_kernel<<<dim3(4, 32), 512, 0, stream>>>(dwn, Wob, pos, wts, out);
}